// Round 2
// baseline (1241.869 us; speedup 1.0000x reference)
//
#include <hip/hip_runtime.h>
#include <hip/hip_bf16.h>

// SoftMoE dims: B=4, M=1024, D=768, E=16, P=64, F=3072, EP=1024, rows=B*M=4096
// d_out (float32): outputs[4,1024,768] | probs[4,1024,16] | tops[4,1024,1] | hidden[4,16,64,3072]

#define BM 128
#define BN 64
#define BK 16

__device__ __forceinline__ float gelu_f(float x) {
    const float c = 0.7978845608028654f;  // sqrt(2/pi)
    float u = c * (x + 0.044715f * x * x * x);
    return 0.5f * x * (1.0f + tanhf(u));
}

// Generic fp32 GEMM: C[row,col] = sum_k A[row,k]*B[k,col] (+bias) (+gelu)
// Grouped row addressing: addr = (row>>6)*rgs + (row&63)*ld + k, covering both
// plain row-major (rgs = 64*ld) and [b][n][p][*] expert layouts (rows=b*64+p,
// blockIdx.z = n). TRANSA: A[row,k] = A[k*lda + row] (mix = dispatch^T @ x).
template<bool TRANSA, bool DOGELU>
__global__ __launch_bounds__(256)
void gemm_k(const float* __restrict__ A, const float* __restrict__ Bm,
            const float* __restrict__ bias, float* __restrict__ C,
            int K, int lda, int ldb, int ldc,
            long aZ, long bZ, long cZ, int biasZ,
            long rgsA, long rgsC)
{
    __shared__ float As[BK][BM];   // [k][i]
    __shared__ float Bs[BK][BN];   // [k][j]
    const int z = blockIdx.z;
    A  += (long)z * aZ;
    Bm += (long)z * bZ;
    if (bias) bias += (long)z * biasZ;
    const int row0 = blockIdx.y * BM;
    const int col0 = blockIdx.x * BN;
    const int t  = threadIdx.x;
    const int tx = t & 15;   // 4 cols
    const int ty = t >> 4;   // 8 rows

    float acc[8][4];
    #pragma unroll
    for (int i = 0; i < 8; ++i)
        #pragma unroll
        for (int j = 0; j < 4; ++j) acc[i][j] = 0.f;

    for (int k0 = 0; k0 < K; k0 += BK) {
        if (TRANSA) {
            const int kk = t >> 5;          // 0..7 (and +8)
            const int ii = (t & 31) * 4;    // 0..124
            const float* pa = A + (long)(k0 + kk) * lda + (row0 + ii);
            float4 v0 = *(const float4*)pa;
            float4 v1 = *(const float4*)(pa + 8L * lda);
            *(float4*)&As[kk][ii]     = v0;
            *(float4*)&As[kk + 8][ii] = v1;
        } else {
            const int ii = t >> 1;          // 0..127
            const int kk = (t & 1) * 8;     // 0 or 8
            const int grow = row0 + ii;
            const float* pa = A + (long)(grow >> 6) * rgsA
                                + (long)(grow & 63) * lda + (k0 + kk);
            float4 v0 = *(const float4*)pa;
            float4 v1 = *(const float4*)(pa + 4);
            As[kk+0][ii] = v0.x; As[kk+1][ii] = v0.y;
            As[kk+2][ii] = v0.z; As[kk+3][ii] = v0.w;
            As[kk+4][ii] = v1.x; As[kk+5][ii] = v1.y;
            As[kk+6][ii] = v1.z; As[kk+7][ii] = v1.w;
        }
        {
            const int kk = t >> 4;          // 0..15
            const int jj = (t & 15) * 4;    // 0..60
            float4 v = *(const float4*)(Bm + (long)(k0 + kk) * ldb + (col0 + jj));
            *(float4*)&Bs[kk][jj] = v;
        }
        __syncthreads();
        #pragma unroll
        for (int k = 0; k < BK; ++k) {
            float a[8], b[4];
            *(float4*)&a[0] = *(const float4*)&As[k][ty * 8];
            *(float4*)&a[4] = *(const float4*)&As[k][ty * 8 + 4];
            *(float4*)&b[0] = *(const float4*)&Bs[k][tx * 4];
            #pragma unroll
            for (int i = 0; i < 8; ++i)
                #pragma unroll
                for (int j = 0; j < 4; ++j)
                    acc[i][j] = fmaf(a[i], b[j], acc[i][j]);
        }
        __syncthreads();
    }

    float bj[4] = {0.f, 0.f, 0.f, 0.f};
    if (bias) {
        #pragma unroll
        for (int j = 0; j < 4; ++j) bj[j] = bias[col0 + tx * 4 + j];
    }
    #pragma unroll
    for (int i = 0; i < 8; ++i) {
        const int grow = row0 + ty * 8 + i;
        const long rb = (long)(grow >> 6) * rgsC
                      + (long)(grow & 63) * ldc + (col0 + tx * 4);
        float4 r;
        float rv[4];
        #pragma unroll
        for (int j = 0; j < 4; ++j) {
            float v = acc[i][j] + bj[j];
            if (DOGELU) v = gelu_f(v);
            rv[j] = v;
        }
        r = make_float4(rv[0], rv[1], rv[2], rv[3]);
        *(float4*)(C + (long)z * cZ + rb) = r;
    }
}

// dispatch = softmax over tokens m (axis=1), IN PLACE on logits.
// logits [B][M=1024][EP=1024]. grid (64, B), block 1024 = 64 m-groups x 16 cols.
// Each thread owns exactly its 16 (m,col) elements -> in-place is race-free.
__global__ __launch_bounds__(1024)
void softmax_m(float* __restrict__ logits)
{
    const int b   = blockIdx.y;
    const int c   = threadIdx.x & 15;
    const int col = blockIdx.x * 16 + c;
    const int mg  = threadIdx.x >> 4;   // 0..63
    float* base = logits + (long)b * 1048576 + col;

    float vals[16];
    float mx = -3.4e38f;
    #pragma unroll
    for (int i = 0; i < 16; ++i) {
        float v = base[(long)(mg * 16 + i) * 1024];
        vals[i] = v;
        mx = fmaxf(mx, v);
    }
    __shared__ float red[64][16];
    red[mg][c] = mx;
    __syncthreads();
    for (int s = 32; s >= 1; s >>= 1) {
        if (mg < s) red[mg][c] = fmaxf(red[mg][c], red[mg + s][c]);
        __syncthreads();
    }
    mx = red[0][c];
    __syncthreads();

    float ssum = 0.f;
    #pragma unroll
    for (int i = 0; i < 16; ++i) {
        vals[i] = expf(vals[i] - mx);
        ssum += vals[i];
    }
    red[mg][c] = ssum;
    __syncthreads();
    for (int s = 32; s >= 1; s >>= 1) {
        if (mg < s) red[mg][c] += red[mg + s][c];
        __syncthreads();
    }
    const float inv = 1.f / red[0][c];

    #pragma unroll
    for (int i = 0; i < 16; ++i)
        base[(long)(mg * 16 + i) * 1024] = vals[i] * inv;
}

// combine = softmax over (e,p) per (b,m); also probabilities (mean over p,
// fp32) and top_experts (argmax over e, fp32). One block per row, 256 thr.
__global__ __launch_bounds__(256)
void softmax_ep(const float* __restrict__ logits, float* __restrict__ comb,
                float* __restrict__ probs, float* __restrict__ tops)
{
    const long r = blockIdx.x;            // b*1024 + m
    const int  t = threadIdx.x;
    const float* row = logits + r * 1024;
    float4 v = *(const float4*)(row + t * 4);

    float mx = fmaxf(fmaxf(v.x, v.y), fmaxf(v.z, v.w));
    #pragma unroll
    for (int s = 32; s; s >>= 1) mx = fmaxf(mx, __shfl_xor(mx, s));
    __shared__ float wr[4];
    const int wid = t >> 6;
    if ((t & 63) == 0) wr[wid] = mx;
    __syncthreads();
    mx = fmaxf(fmaxf(wr[0], wr[1]), fmaxf(wr[2], wr[3]));
    __syncthreads();

    float e0 = expf(v.x - mx), e1 = expf(v.y - mx);
    float e2 = expf(v.z - mx), e3 = expf(v.w - mx);
    float s4 = e0 + e1 + e2 + e3;
    float sm = s4;
    #pragma unroll
    for (int s = 32; s; s >>= 1) sm += __shfl_xor(sm, s);
    if ((t & 63) == 0) wr[wid] = sm;
    __syncthreads();
    const float tot = wr[0] + wr[1] + wr[2] + wr[3];
    const float inv = 1.f / tot;

    float4 o;
    o.x = e0 * inv; o.y = e1 * inv; o.z = e2 * inv; o.w = e3 * inv;
    *(float4*)(comb + r * 1024 + t * 4) = o;

    // per-expert sums: thread t's 4 elems (ep=4t..4t+3) all in expert t>>4
    __shared__ float es[16][16];
    es[t >> 4][t & 15] = s4 * inv;
    __syncthreads();
    __shared__ float pr[16];
    if (t < 16) {
        float ss = 0.f;
        #pragma unroll
        for (int i = 0; i < 16; ++i) ss += es[t][i];
        float p = ss * (1.f / 64.f);
        probs[r * 16 + t] = p;
        pr[t] = p;
    }
    __syncthreads();
    if (t == 0) {
        int best = 0; float bv = pr[0];
        #pragma unroll
        for (int e = 1; e < 16; ++e)
            if (pr[e] > bv) { bv = pr[e]; best = e; }
        tops[r] = (float)best;
    }
}

extern "C" void kernel_launch(void* const* d_in, const int* in_sizes, int n_in,
                              void* d_out, int out_size, void* d_ws, size_t ws_size,
                              hipStream_t stream)
{
    (void)in_sizes; (void)n_in; (void)out_size; (void)ws_size;
    const float* x   = (const float*)d_in[0];   // [4,1024,768]
    const float* phi = (const float*)d_in[1];   // [768,16,64]
    const float* W1  = (const float*)d_in[2];   // [16,768,3072]
    const float* b1  = (const float*)d_in[3];   // [16,3072]
    const float* W2  = (const float*)d_in[4];   // [16,3072,768]
    const float* b2  = (const float*)d_in[5];   // [16,768]

    float* outputs = (float*)d_out;                     // [4,1024,768]
    float* probs   = outputs + 3145728;                 // [4,1024,16]
    float* tops    = outputs + 3145728 + 65536;         // [4,1024,1]
    float* hid     = outputs + 3145728 + 65536 + 4096;  // [4,16,64,3072] fp32

    float* ws     = (float*)d_ws;
    float* logits = ws;                 // [4096,1024]; becomes disp in-place
    float* comb   = ws + 4194304;       // [4096,1024]
    float* mixb   = ws + 8388608;       // [4,1024(ep),768]
    float* eout   = ws;                 // [4,16,64,768] aliases dead disp
    // ws total: 11,534,336 floats = 44 MiB

    // K1: logits = x @ phi   [4096x768]·[768x1024]
    gemm_k<false, false><<<dim3(16, 32, 1), 256, 0, stream>>>(
        x, phi, nullptr, logits,
        768, 768, 1024, 1024, 0L, 0L, 0L, 0, 64L * 768, 64L * 1024);

    // K2b: combine softmax over ep + probabilities + argmax (reads raw logits)
    softmax_ep<<<dim3(4096), 256, 0, stream>>>(logits, comb, probs, tops);

    // K2a: dispatch softmax over m, in place (logits -> disp)
    softmax_m<<<dim3(64, 4), 1024, 0, stream>>>(logits);

    // K3: mix[b] = disp[b]^T @ x[b]   (z=b) -> mixb[b][ep][d]
    gemm_k<true, false><<<dim3(12, 8, 4), 256, 0, stream>>>(
        logits, x, nullptr, mixb,
        1024, 1024, 768, 768, 1048576L, 786432L, 786432L, 0, 0L, 64L * 768);

    // K4: hidden = gelu(mix @ W1 + b1) -> d_out hidden region (z=n, rows=b*64+p)
    gemm_k<false, true><<<dim3(48, 2, 16), 256, 0, stream>>>(
        mixb, W1, b1, hid,
        768, 768, 3072, 3072, 49152L, 2359296L, 196608L, 3072,
        786432L, 3145728L);

    // K5: eout = hidden @ W2 + b2   (z=n, M=256, N=768, K=3072)
    gemm_k<false, false><<<dim3(12, 2, 16), 256, 0, stream>>>(
        hid, W2, b2, eout,
        3072, 3072, 768, 768, 196608L, 2359296L, 49152L, 768,
        3145728L, 786432L);

    // K6: out[b] = comb[b] @ eout[b]   (z=b, M=1024, N=768, K=1024)
    gemm_k<false, false><<<dim3(12, 8, 4), 256, 0, stream>>>(
        comb, eout, nullptr, outputs,
        1024, 1024, 768, 768, 1048576L, 786432L, 786432L, 0,
        64L * 1024, 64L * 768);
}

// Round 3
// 692.665 us; speedup vs baseline: 1.7929x; 1.7929x over previous
//
#include <hip/hip_runtime.h>
#include <hip/hip_bf16.h>

// SoftMoE: B=4, M=1024, D=768, E=16, P=64, F=3072, EP=1024, rows=B*M=4096
// d_out (fp32): outputs[4,1024,768] | probs[4,1024,16] | tops[4,1024,1] | hidden[4,16,64,3072]

typedef unsigned short u16;
typedef __bf16 bf16x8 __attribute__((ext_vector_type(8)));
typedef float f32x4 __attribute__((ext_vector_type(4)));

__device__ __forceinline__ float gelu_f(float x) {
    const float c = 0.7978845608028654f;  // sqrt(2/pi)
    float u = c * (x + 0.044715f * x * x * x);
    return 0.5f * x * (1.0f + tanhf(u));
}

__device__ __forceinline__ u16 f2b(float x) {
    union { float f; unsigned u; } v; v.f = x;
    unsigned r = v.u + 0x7FFF + ((v.u >> 16) & 1);
    return (u16)(r >> 16);
}

// ---------------------------------------------------------------------------
// fp32 GEMM (round-1, proven). Used for K1 always; K3-K6 on the fallback path.
// addr = z*aZ + (row>>6)*rgs + (row&63)*ld + k
template<bool TRANSA, bool DOGELU>
__global__ __launch_bounds__(256)
void gemm_k(const float* __restrict__ A, const float* __restrict__ Bm,
            const float* __restrict__ bias, float* __restrict__ C,
            int K, int lda, int ldb, int ldc,
            long aZ, long bZ, long cZ, int biasZ,
            long rgsA, long rgsC)
{
    __shared__ float As[16][128];
    __shared__ float Bs[16][64];
    const int z = blockIdx.z;
    A  += (long)z * aZ;
    Bm += (long)z * bZ;
    if (bias) bias += (long)z * biasZ;
    const int row0 = blockIdx.y * 128;
    const int col0 = blockIdx.x * 64;
    const int t  = threadIdx.x;
    const int tx = t & 15;
    const int ty = t >> 4;

    float acc[8][4];
    #pragma unroll
    for (int i = 0; i < 8; ++i)
        #pragma unroll
        for (int j = 0; j < 4; ++j) acc[i][j] = 0.f;

    for (int k0 = 0; k0 < K; k0 += 16) {
        if (TRANSA) {
            const int kk = t >> 5;
            const int ii = (t & 31) * 4;
            const float* pa = A + (long)(k0 + kk) * lda + (row0 + ii);
            float4 v0 = *(const float4*)pa;
            float4 v1 = *(const float4*)(pa + 8L * lda);
            *(float4*)&As[kk][ii]     = v0;
            *(float4*)&As[kk + 8][ii] = v1;
        } else {
            const int ii = t >> 1;
            const int kk = (t & 1) * 8;
            const int grow = row0 + ii;
            const float* pa = A + (long)(grow >> 6) * rgsA
                                + (long)(grow & 63) * lda + (k0 + kk);
            float4 v0 = *(const float4*)pa;
            float4 v1 = *(const float4*)(pa + 4);
            As[kk+0][ii] = v0.x; As[kk+1][ii] = v0.y;
            As[kk+2][ii] = v0.z; As[kk+3][ii] = v0.w;
            As[kk+4][ii] = v1.x; As[kk+5][ii] = v1.y;
            As[kk+6][ii] = v1.z; As[kk+7][ii] = v1.w;
        }
        {
            const int kk = t >> 4;
            const int jj = (t & 15) * 4;
            float4 v = *(const float4*)(Bm + (long)(k0 + kk) * ldb + (col0 + jj));
            *(float4*)&Bs[kk][jj] = v;
        }
        __syncthreads();
        #pragma unroll
        for (int k = 0; k < 16; ++k) {
            float a[8], b[4];
            *(float4*)&a[0] = *(const float4*)&As[k][ty * 8];
            *(float4*)&a[4] = *(const float4*)&As[k][ty * 8 + 4];
            *(float4*)&b[0] = *(const float4*)&Bs[k][tx * 4];
            #pragma unroll
            for (int i = 0; i < 8; ++i)
                #pragma unroll
                for (int j = 0; j < 4; ++j)
                    acc[i][j] = fmaf(a[i], b[j], acc[i][j]);
        }
        __syncthreads();
    }

    float bj[4] = {0.f, 0.f, 0.f, 0.f};
    if (bias) {
        #pragma unroll
        for (int j = 0; j < 4; ++j) bj[j] = bias[col0 + tx * 4 + j];
    }
    #pragma unroll
    for (int i = 0; i < 8; ++i) {
        const int grow = row0 + ty * 8 + i;
        const long rb = (long)(grow >> 6) * rgsC
                      + (long)(grow & 63) * ldc + (col0 + tx * 4);
        float rv[4];
        #pragma unroll
        for (int j = 0; j < 4; ++j) {
            float v = acc[i][j] + bj[j];
            if (DOGELU) v = gelu_f(v);
            rv[j] = v;
        }
        *(float4*)(C + (long)z * cZ + rb) = make_float4(rv[0], rv[1], rv[2], rv[3]);
    }
}

// ---------------------------------------------------------------------------
// bf16 MFMA GEMM. 128x128 tile, BK=64, 256 thr = 4 waves (2x2), 64x64/wave as
// 4x4 of v_mfma_f32_16x16x32_bf16. LDS [dim][64] bf16 with XOR chunk swizzle
// (chunk ^= row&7) -> conflict-free b128 staging writes AND fragment reads.
// A: bf16 or fp32 (converted in staging), grouped rows. B: bf16 [n][k].
template<bool AF32, bool DOGELU, bool CF32>
__global__ __launch_bounds__(256)
void mfma_gemm(const void* __restrict__ Av, const u16* __restrict__ Bt,
               const float* __restrict__ bias, void* __restrict__ Cv,
               int K, int lda, int ldb, int ldc,
               long aZ, long bZ, long cZ, int biasZ,
               long rgsA, long rgsC)
{
    __shared__ u16 As[128][64];
    __shared__ u16 Bs[128][64];
    const int z    = blockIdx.z;
    const int row0 = blockIdx.y * 128;
    const int col0 = blockIdx.x * 128;
    const int t    = threadIdx.x;
    const int lane = t & 63;
    const int wave = t >> 6;
    const int wr   = (wave >> 1) * 64;
    const int wc   = (wave & 1) * 64;

    const int srow  = t >> 1;   // staging row 0..127
    const int shalf = t & 1;    // which 32-elem k half
    const int agrow = row0 + srow;
    const long aRowOff = (long)z * aZ + (long)(agrow >> 6) * rgsA
                       + (long)(agrow & 63) * lda;
    const long bRowOff = (long)z * bZ + (long)(col0 + srow) * ldb;

    f32x4 acc[4][4] = {};

    for (int k0 = 0; k0 < K; k0 += 64) {
        // --- stage A ---
        if (AF32) {
            const float* pa = (const float*)Av + aRowOff + k0 + shalf * 32;
            #pragma unroll
            for (int q = 0; q < 4; ++q) {
                float4 u0 = *(const float4*)(pa + q * 8);
                float4 u1 = *(const float4*)(pa + q * 8 + 4);
                u16 tmp[8] = { f2b(u0.x), f2b(u0.y), f2b(u0.z), f2b(u0.w),
                               f2b(u1.x), f2b(u1.y), f2b(u1.z), f2b(u1.w) };
                const int cs = (shalf * 4 + q) ^ (srow & 7);
                *(uint4*)&As[srow][cs * 8] = *(const uint4*)tmp;
            }
        } else {
            const u16* pa = (const u16*)Av + aRowOff + k0 + shalf * 32;
            #pragma unroll
            for (int q = 0; q < 4; ++q) {
                uint4 v = *(const uint4*)(pa + q * 8);
                const int cs = (shalf * 4 + q) ^ (srow & 7);
                *(uint4*)&As[srow][cs * 8] = v;
            }
        }
        // --- stage B (always bf16 [n][k]) ---
        {
            const u16* pb = Bt + bRowOff + k0 + shalf * 32;
            #pragma unroll
            for (int q = 0; q < 4; ++q) {
                uint4 v = *(const uint4*)(pb + q * 8);
                const int cs = (shalf * 4 + q) ^ (srow & 7);
                *(uint4*)&Bs[srow][cs * 8] = v;
            }
        }
        __syncthreads();

        #pragma unroll
        for (int kk = 0; kk < 2; ++kk) {
            const int cchunk = kk * 4 + (lane >> 4);   // k chunk 0..7
            bf16x8 af[4], bfr[4];
            #pragma unroll
            for (int i = 0; i < 4; ++i) {
                const int m = wr + i * 16 + (lane & 15);
                af[i]  = __builtin_bit_cast(bf16x8,
                           *(const uint4*)&As[m][(cchunk ^ (m & 7)) * 8]);
                const int n = wc + i * 16 + (lane & 15);
                bfr[i] = __builtin_bit_cast(bf16x8,
                           *(const uint4*)&Bs[n][(cchunk ^ (n & 7)) * 8]);
            }
            #pragma unroll
            for (int i = 0; i < 4; ++i)
                #pragma unroll
                for (int j = 0; j < 4; ++j)
                    acc[i][j] = __builtin_amdgcn_mfma_f32_16x16x32_bf16(
                                    af[i], bfr[j], acc[i][j], 0, 0, 0);
        }
        __syncthreads();
    }

    // --- epilogue: C/D layout col=lane&15, row=(lane>>4)*4+reg ---
    const int cq = lane >> 4;
    #pragma unroll
    for (int j = 0; j < 4; ++j) {
        const int gcol = col0 + wc + j * 16 + (lane & 15);
        const float bv = bias ? bias[(long)z * biasZ + gcol] : 0.f;
        #pragma unroll
        for (int i = 0; i < 4; ++i) {
            #pragma unroll
            for (int r = 0; r < 4; ++r) {
                const int grow = row0 + wr + i * 16 + cq * 4 + r;
                const long co = (long)z * cZ + (long)(grow >> 6) * rgsC
                              + (long)(grow & 63) * ldc + gcol;
                float v = acc[i][j][r] + bv;
                if (DOGELU) v = gelu_f(v);
                if (CF32) ((float*)Cv)[co] = v;
                else      ((u16*)Cv)[co]  = f2b(v);
            }
        }
    }
}

// ---------------------------------------------------------------------------
// Transpose [z][R][C] (fp32 or bf16) -> [z][C][R] bf16. 64x64 tiles, 256 thr.
template<bool F32>
__global__ __launch_bounds__(256)
void transpose_k(const void* __restrict__ inV, u16* __restrict__ out, int R, int C)
{
    __shared__ u16 tile[64][72];
    const long zin = (long)blockIdx.z * R * C;
    const int r0 = blockIdx.y * 64, c0 = blockIdx.x * 64;
    const int t  = threadIdx.x;
    const int tr = t >> 4;
    const int tc = (t & 15) * 4;
    #pragma unroll
    for (int p = 0; p < 4; ++p) {
        const int r = tr + p * 16;
        if (F32) {
            float4 v = *(const float4*)((const float*)inV + zin + (long)(r0 + r) * C + c0 + tc);
            tile[r][tc+0] = f2b(v.x); tile[r][tc+1] = f2b(v.y);
            tile[r][tc+2] = f2b(v.z); tile[r][tc+3] = f2b(v.w);
        } else {
            ushort4 v = *(const ushort4*)((const u16*)inV + zin + (long)(r0 + r) * C + c0 + tc);
            tile[r][tc+0] = v.x; tile[r][tc+1] = v.y;
            tile[r][tc+2] = v.z; tile[r][tc+3] = v.w;
        }
    }
    __syncthreads();
    #pragma unroll
    for (int p = 0; p < 4; ++p) {
        const int rr = tr + p * 16;
        ushort4 o;
        o.x = tile[tc+0][rr]; o.y = tile[tc+1][rr];
        o.z = tile[tc+2][rr]; o.w = tile[tc+3][rr];
        *(ushort4*)(out + (long)blockIdx.z * R * C + (long)(c0 + rr) * R + r0 + tc) = o;
    }
}

// ---------------------------------------------------------------------------
// dispatch softmax over m, in place (fallback path)
__global__ __launch_bounds__(1024)
void softmax_m(float* __restrict__ logits)
{
    const int b   = blockIdx.y;
    const int c   = threadIdx.x & 15;
    const int col = blockIdx.x * 16 + c;
    const int mg  = threadIdx.x >> 4;
    float* base = logits + (long)b * 1048576 + col;

    float vals[16];
    float mx = -3.4e38f;
    #pragma unroll
    for (int i = 0; i < 16; ++i) {
        float v = base[(long)(mg * 16 + i) * 1024];
        vals[i] = v;
        mx = fmaxf(mx, v);
    }
    __shared__ float red[64][16];
    red[mg][c] = mx;
    __syncthreads();
    for (int s = 32; s >= 1; s >>= 1) {
        if (mg < s) red[mg][c] = fmaxf(red[mg][c], red[mg + s][c]);
        __syncthreads();
    }
    mx = red[0][c];
    __syncthreads();
    float ssum = 0.f;
    #pragma unroll
    for (int i = 0; i < 16; ++i) { vals[i] = expf(vals[i] - mx); ssum += vals[i]; }
    red[mg][c] = ssum;
    __syncthreads();
    for (int s = 32; s >= 1; s >>= 1) {
        if (mg < s) red[mg][c] += red[mg + s][c];
        __syncthreads();
    }
    const float inv = 1.f / red[0][c];
    #pragma unroll
    for (int i = 0; i < 16; ++i)
        base[(long)(mg * 16 + i) * 1024] = vals[i] * inv;
}

// dispatch softmax over m -> dispT[b][ep][m] bf16 (MFMA path; logits untouched)
__global__ __launch_bounds__(1024)
void softmax_mT(const float* __restrict__ logits, u16* __restrict__ dispT)
{
    const int b   = blockIdx.y;
    const int c   = threadIdx.x & 15;
    const int col = blockIdx.x * 16 + c;
    const int mg  = threadIdx.x >> 4;
    const float* base = logits + (long)b * 1048576 + col;

    float vals[16];
    float mx = -3.4e38f;
    #pragma unroll
    for (int i = 0; i < 16; ++i) {
        float v = base[(long)(mg * 16 + i) * 1024];
        vals[i] = v;
        mx = fmaxf(mx, v);
    }
    __shared__ float red[64][16];
    red[mg][c] = mx;
    __syncthreads();
    for (int s = 32; s >= 1; s >>= 1) {
        if (mg < s) red[mg][c] = fmaxf(red[mg][c], red[mg + s][c]);
        __syncthreads();
    }
    mx = red[0][c];
    __syncthreads();
    float ssum = 0.f;
    #pragma unroll
    for (int i = 0; i < 16; ++i) { vals[i] = expf(vals[i] - mx); ssum += vals[i]; }
    red[mg][c] = ssum;
    __syncthreads();
    for (int s = 32; s >= 1; s >>= 1) {
        if (mg < s) red[mg][c] += red[mg + s][c];
        __syncthreads();
    }
    const float inv = 1.f / red[0][c];

    union { u16 s[16]; uint4 q[2]; } pk;
    #pragma unroll
    for (int i = 0; i < 16; ++i) pk.s[i] = f2b(vals[i] * inv);
    u16* ob = dispT + (long)b * 1048576 + (long)col * 1024 + mg * 16;
    *(uint4*)ob       = pk.q[0];
    *(uint4*)(ob + 8) = pk.q[1];
}

// combine softmax over (e,p), + probabilities (fp32-exact) + argmax (fp32-exact)
template<bool B16>
__global__ __launch_bounds__(256)
void softmax_ep(const float* __restrict__ logits, void* __restrict__ comb,
                float* __restrict__ probs, float* __restrict__ tops)
{
    const long r = blockIdx.x;
    const int  t = threadIdx.x;
    const float* row = logits + r * 1024;
    float4 v = *(const float4*)(row + t * 4);

    float mx = fmaxf(fmaxf(v.x, v.y), fmaxf(v.z, v.w));
    #pragma unroll
    for (int s = 32; s; s >>= 1) mx = fmaxf(mx, __shfl_xor(mx, s));
    __shared__ float wr_[4];
    const int wid = t >> 6;
    if ((t & 63) == 0) wr_[wid] = mx;
    __syncthreads();
    mx = fmaxf(fmaxf(wr_[0], wr_[1]), fmaxf(wr_[2], wr_[3]));
    __syncthreads();

    float e0 = expf(v.x - mx), e1 = expf(v.y - mx);
    float e2 = expf(v.z - mx), e3 = expf(v.w - mx);
    float s4 = e0 + e1 + e2 + e3;
    float sm = s4;
    #pragma unroll
    for (int s = 32; s; s >>= 1) sm += __shfl_xor(sm, s);
    if ((t & 63) == 0) wr_[wid] = sm;
    __syncthreads();
    const float tot = wr_[0] + wr_[1] + wr_[2] + wr_[3];
    const float inv = 1.f / tot;

    if (B16) {
        ushort4 o;
        o.x = f2b(e0 * inv); o.y = f2b(e1 * inv);
        o.z = f2b(e2 * inv); o.w = f2b(e3 * inv);
        *(ushort4*)((u16*)comb + r * 1024 + t * 4) = o;
    } else {
        float4 o = make_float4(e0 * inv, e1 * inv, e2 * inv, e3 * inv);
        *(float4*)((float*)comb + r * 1024 + t * 4) = o;
    }

    __shared__ float es[16][16];
    es[t >> 4][t & 15] = s4 * inv;
    __syncthreads();
    __shared__ float pr[16];
    if (t < 16) {
        float ss = 0.f;
        #pragma unroll
        for (int i = 0; i < 16; ++i) ss += es[t][i];
        float p = ss * (1.f / 64.f);
        probs[r * 16 + t] = p;
        pr[t] = p;
    }
    __syncthreads();
    if (t == 0) {
        int best = 0; float bv = pr[0];
        #pragma unroll
        for (int e = 1; e < 16; ++e)
            if (pr[e] > bv) { bv = pr[e]; best = e; }
        tops[r] = (float)best;
    }
}

// ---------------------------------------------------------------------------
extern "C" void kernel_launch(void* const* d_in, const int* in_sizes, int n_in,
                              void* d_out, int out_size, void* d_ws, size_t ws_size,
                              hipStream_t stream)
{
    (void)in_sizes; (void)n_in; (void)out_size;
    const float* x   = (const float*)d_in[0];
    const float* phi = (const float*)d_in[1];
    const float* W1  = (const float*)d_in[2];
    const float* b1  = (const float*)d_in[3];
    const float* W2  = (const float*)d_in[4];
    const float* b2  = (const float*)d_in[5];

    float* outputs = (float*)d_out;
    float* probs   = outputs + 3145728;
    float* tops    = outputs + 3145728 + 65536;
    float* hid     = outputs + 3145728 + 65536 + 4096;   // [4][16][64][3072] fp32

    char* wsb = (char*)d_ws;

    if (ws_size >= 209715200ull) {
        // ================= MFMA path (needs 200 MiB ws) =================
        float* logits = (float*)(wsb);                    // 16 MiB
        u16*   combB  = (u16*)(wsb + 16777216);           // 8 MiB
        u16*   dispT  = (u16*)(wsb + 25165824);           // 8 MiB
        u16*   xT     = (u16*)(wsb + 33554432);           // 6 MiB
        u16*   mixB   = (u16*)(wsb + 39845888);           // 6 MiB
        u16*   W1T    = (u16*)(wsb + 46137344);           // 72 MiB
        u16*   W2T    = (u16*)(wsb + 121634816);          // 72 MiB
        u16*   eoutN  = (u16*)(wsb + 197132288);          // 6 MiB
        u16*   eoutT  = (u16*)(wsb + 203423744);          // 6 MiB

        // T1-T3: W1 -> W1T[e][f][d], W2 -> W2T[e][d][f], x -> xT[b][d][m]
        transpose_k<true><<<dim3(48, 12, 16), 256, 0, stream>>>(W1, W1T, 768, 3072);
        transpose_k<true><<<dim3(12, 48, 16), 256, 0, stream>>>(W2, W2T, 3072, 768);
        transpose_k<true><<<dim3(12, 16, 4),  256, 0, stream>>>(x,  xT,  1024, 768);

        // K1: logits = x @ phi (fp32 — keeps probabilities/argmax exact)
        gemm_k<false, false><<<dim3(16, 32, 1), 256, 0, stream>>>(
            x, phi, nullptr, logits,
            768, 768, 1024, 1024, 0L, 0L, 0L, 0, 64L * 768, 64L * 1024);

        // K2: combine softmax (bf16 comb + fp32 probs/tops); dispatch softmax -> dispT
        softmax_ep<true><<<dim3(4096), 256, 0, stream>>>(logits, combB, probs, tops);
        softmax_mT<<<dim3(64, 4), 1024, 0, stream>>>(logits, dispT);

        // K3: mix[b][ep][d] = dispT[b] @ x[b]  (M=1024,N=768,K=1024)
        mfma_gemm<false, false, false><<<dim3(6, 8, 4), 256, 0, stream>>>(
            dispT, xT, nullptr, mixB,
            1024, 1024, 1024, 768, 1048576L, 786432L, 786432L, 0,
            65536L, 49152L);

        // K4: hidden = gelu(mix @ W1 + b1) -> d_out fp32 (M=256,N=3072,K=768, z=e)
        mfma_gemm<false, true, true><<<dim3(24, 2, 16), 256, 0, stream>>>(
            mixB, W1T, b1, hid,
            768, 768, 768, 3072, 49152L, 2359296L, 196608L, 3072,
            786432L, 3145728L);

        // K5: eout = hidden @ W2 + b2 (A=fp32 from d_out; M=256,N=768,K=3072, z=e)
        mfma_gemm<true, false, false><<<dim3(6, 2, 16), 256, 0, stream>>>(
            hid, W2T, b2, eoutN,
            3072, 3072, 3072, 768, 196608L, 2359296L, 49152L, 768,
            3145728L, 786432L);

        // T4: eoutN[b][ep][d] -> eoutT[b][d][ep]
        transpose_k<false><<<dim3(12, 16, 4), 256, 0, stream>>>(eoutN, eoutT, 1024, 768);

        // K6: outputs[b] = combB[b] @ eoutT[b]  (M=1024,N=768,K=1024)
        mfma_gemm<false, false, true><<<dim3(6, 8, 4), 256, 0, stream>>>(
            combB, eoutT, nullptr, outputs,
            1024, 1024, 1024, 768, 1048576L, 786432L, 786432L, 0,
            65536L, 49152L);
    } else {
        // ================= fallback: round-1 fp32 path (44 MiB ws) =================
        float* logits = (float*)wsb;                  // becomes disp in place
        float* comb   = (float*)(wsb + 16777216);
        float* mixb   = (float*)(wsb + 33554432);
        float* eout   = (float*)wsb;                  // aliases dead disp

        gemm_k<false, false><<<dim3(16, 32, 1), 256, 0, stream>>>(
            x, phi, nullptr, logits,
            768, 768, 1024, 1024, 0L, 0L, 0L, 0, 64L * 768, 64L * 1024);
        softmax_ep<false><<<dim3(4096), 256, 0, stream>>>(logits, comb, probs, tops);
        softmax_m<<<dim3(64, 4), 1024, 0, stream>>>(logits);
        gemm_k<true, false><<<dim3(12, 8, 4), 256, 0, stream>>>(
            logits, x, nullptr, mixb,
            1024, 1024, 768, 768, 1048576L, 786432L, 786432L, 0, 0L, 64L * 768);
        gemm_k<false, true><<<dim3(48, 2, 16), 256, 0, stream>>>(
            mixb, W1, b1, hid,
            768, 768, 3072, 3072, 49152L, 2359296L, 196608L, 3072,
            786432L, 3145728L);
        gemm_k<false, false><<<dim3(12, 2, 16), 256, 0, stream>>>(
            hid, W2, b2, eout,
            3072, 3072, 768, 768, 196608L, 2359296L, 49152L, 768,
            3145728L, 786432L);
        gemm_k<false, false><<<dim3(12, 8, 4), 256, 0, stream>>>(
            comb, eout, nullptr, outputs,
            1024, 1024, 768, 768, 1048576L, 786432L, 786432L, 0,
            64L * 1024, 64L * 768);
    }
}